// Round 1
// baseline (1492.574 us; speedup 1.0000x reference)
//
#include <hip/hip_runtime.h>
#include <math.h>

#define HIDDEN 96
#define NNODES 50000
#define NEDGES 800000
#define INDIM  256
#define RS 0.07216878364870323f   // 1/sqrt(2*HIDDEN)

// ---------------------------------------------------------------------------
// Repack W_gate [96][192] into V [192][96] with V[j][k]   = W_gate[j][k]    *RS (j<96)
//                                             V[96+j][k] = W_gate[j][96+k] *RS
// and bias2[192] = [b_gate*RS, 0]. Folding the 1/sqrt(192) scale and bias here
// lets the edge kernel be tanh(pd + ps) with zero extra math.
// ---------------------------------------------------------------------------
__global__ void repack_kernel(const float* __restrict__ Wg, const float* __restrict__ bg,
                              float* __restrict__ V, float* __restrict__ bias2) {
    int idx = blockIdx.x * 256 + threadIdx.x;
    if (idx < 192 * 96) {
        int j = idx / 96, k = idx % 96;
        float v = (j < 96) ? Wg[j * 192 + k] : Wg[(j - 96) * 192 + 96 + k];
        V[idx] = v * RS;
    }
    if (idx < 192) bias2[idx] = (idx < 96) ? bg[idx] * RS : 0.0f;
}

// ---------------------------------------------------------------------------
// C[M][ldc] tile = A[M][K] @ B[NB][K]^T + bias.  BM=64, BN=96, BK=32.
// 256 threads, 4x6 micro-tile. te = tid>>4 so A-side LDS reads broadcast
// across the 16 tc-lanes of each wave (free); B-side is 4-way on b128
// (~1.58x, acceptable — FMA still dominates: 96 FMA vs ~162 LDS cyc / 4k).
// ---------------------------------------------------------------------------
__global__ __launch_bounds__(256) void gemm_nt_bias(
    const float* __restrict__ A, const float* __restrict__ B,
    const float* __restrict__ bias, float* __restrict__ C,
    int M, int K, int ldc) {
    __shared__ float As[64][36];
    __shared__ float Bs[96][36];
    const int tid = threadIdx.x;
    const int m0 = blockIdx.x * 64;
    const int n0 = blockIdx.y * 96;
    const int te = tid >> 4;       // 0..15 -> rows 4*te..4*te+3
    const int tc = tid & 15;       // 0..15 -> cols 6*tc..6*tc+5
    const int ra = tid >> 3;       // 0..31 load row
    const int ka = (tid & 7) * 4;  // k offset (float4)

    float acc[4][6];
#pragma unroll
    for (int i = 0; i < 4; i++)
#pragma unroll
        for (int j = 0; j < 6; j++) acc[i][j] = 0.0f;

    for (int k0 = 0; k0 < K; k0 += 32) {
#pragma unroll
        for (int r = 0; r < 2; r++) {
            int row = m0 + ra + r * 32;
            float4 v = make_float4(0, 0, 0, 0);
            if (row < M) v = *(const float4*)&A[(size_t)row * K + k0 + ka];
            *(float4*)&As[ra + r * 32][ka] = v;
        }
#pragma unroll
        for (int r = 0; r < 3; r++) {
            int row = n0 + ra + r * 32;   // always < NB by grid construction
            float4 v = *(const float4*)&B[(size_t)row * K + k0 + ka];
            *(float4*)&Bs[ra + r * 32][ka] = v;
        }
        __syncthreads();
#pragma unroll
        for (int k4 = 0; k4 < 32; k4 += 4) {
            float4 af[4], bf[6];
#pragma unroll
            for (int i = 0; i < 4; i++) af[i] = *(float4*)&As[4 * te + i][k4];
#pragma unroll
            for (int j = 0; j < 6; j++) bf[j] = *(float4*)&Bs[6 * tc + j][k4];
#pragma unroll
            for (int i = 0; i < 4; i++)
#pragma unroll
                for (int j = 0; j < 6; j++)
                    acc[i][j] += af[i].x * bf[j].x + af[i].y * bf[j].y +
                                 af[i].z * bf[j].z + af[i].w * bf[j].w;
        }
        __syncthreads();
    }
#pragma unroll
    for (int i = 0; i < 4; i++) {
        int row = m0 + 4 * te + i;
        if (row < M) {
#pragma unroll
            for (int j = 0; j < 6; j++) {
                int col = n0 + 6 * tc + j;
                C[(size_t)row * ldc + col] = acc[i][j] + bias[col];
            }
        }
    }
}

// ---------------------------------------------------------------------------
// Edge pass: one thread per (edge, float4-chunk); 24 chunks cover 96 cols.
// a[e] = tanh(p_d[dst] + p_s[src]); msg = h[src]*a*(d[dst]*d[src]) scattered
// to z_acc[dst] with fp32 atomics.
// ---------------------------------------------------------------------------
__global__ __launch_bounds__(256) void edge_kernel(
    const float* __restrict__ P, const float* __restrict__ h,
    const float* __restrict__ dvec, const int* __restrict__ src,
    const int* __restrict__ dst, float* __restrict__ a_out,
    float* __restrict__ z_acc) {
    unsigned idx = blockIdx.x * 256u + threadIdx.x;
    if (idx >= (unsigned)NEDGES * 24u) return;
    unsigned e = idx / 24u;
    unsigned c = idx % 24u;
    int s = src[e], t = dst[e];
    float4 pd = *(const float4*)&P[(size_t)t * 192 + 4 * c];
    float4 ps = *(const float4*)&P[(size_t)s * 192 + 96 + 4 * c];
    float4 hs = *(const float4*)&h[(size_t)s * 96 + 4 * c];
    float ee = dvec[t] * dvec[s];
    float4 a4;
    a4.x = tanhf(pd.x + ps.x);
    a4.y = tanhf(pd.y + ps.y);
    a4.z = tanhf(pd.z + ps.z);
    a4.w = tanhf(pd.w + ps.w);
    *(float4*)&a_out[(size_t)e * 96 + 4 * c] = a4;
    float* zp = &z_acc[(size_t)t * 96 + 4 * c];
    atomicAdd(zp + 0, hs.x * a4.x * ee);
    atomicAdd(zp + 1, hs.y * a4.y * ee);
    atomicAdd(zp + 2, hs.z * a4.z * ee);
    atomicAdd(zp + 3, hs.w * a4.w * ee);
}

// ---------------------------------------------------------------------------
// z = log_softmax(z_acc @ W_clf.T + b_clf). One thread per node.
// ---------------------------------------------------------------------------
__global__ __launch_bounds__(256) void clf_kernel(
    const float* __restrict__ z_acc, const float* __restrict__ Wc,
    const float* __restrict__ bc, float* __restrict__ z_out, int N) {
    int n = blockIdx.x * 256 + threadIdx.x;
    if (n >= N) return;
    const float4* zr = (const float4*)&z_acc[(size_t)n * 96];
    const float4* w0 = (const float4*)&Wc[0];
    const float4* w1 = (const float4*)&Wc[96];
    float a0 = 0.f, a1 = 0.f;
#pragma unroll
    for (int c = 0; c < 24; c++) {
        float4 z = zr[c], x0 = w0[c], x1 = w1[c];
        a0 += z.x * x0.x + z.y * x0.y + z.z * x0.z + z.w * x0.w;
        a1 += z.x * x1.x + z.y * x1.y + z.z * x1.z + z.w * x1.w;
    }
    a0 += bc[0];
    a1 += bc[1];
    float m = fmaxf(a0, a1);
    float lse = m + logf(expf(a0 - m) + expf(a1 - m));
    z_out[2 * n + 0] = a0 - lse;
    z_out[2 * n + 1] = a1 - lse;
}

extern "C" void kernel_launch(void* const* d_in, const int* in_sizes, int n_in,
                              void* d_out, int out_size, void* d_ws, size_t ws_size,
                              hipStream_t stream) {
    const float* x    = (const float*)d_in[0];
    const float* dvec = (const float*)d_in[1];
    const int*   src  = (const int*)d_in[2];
    const int*   dst  = (const int*)d_in[3];
    const float* W_in = (const float*)d_in[4];
    const float* b_in = (const float*)d_in[5];
    const float* W_g  = (const float*)d_in[6];
    const float* b_g  = (const float*)d_in[7];
    const float* W_c  = (const float*)d_in[8];
    const float* b_c  = (const float*)d_in[9];

    float* z_out = (float*)d_out;                 // [50000*2]
    float* a_out = (float*)d_out + 2 * NNODES;    // [800000*96]

    char* ws = (char*)d_ws;
    float* h    = (float*)(ws);                   // 50000*96*4  = 19,200,000 B
    float* P    = (float*)(ws + 19200000);        // 50000*192*4 = 38,400,000 B
    float* V    = (float*)(ws + 57600000);        // 192*96*4    = 73,728 B
    float* b2   = (float*)(ws + 57673728);        // 192*4       = 768 B
    float* zac  = (float*)(ws + 57674496);        // 50000*96*4  = 19,200,000 B
    // total 76,874,496 B of workspace

    hipMemsetAsync(zac, 0, (size_t)NNODES * HIDDEN * sizeof(float), stream);
    repack_kernel<<<dim3((192 * 96 + 255) / 256), 256, 0, stream>>>(W_g, b_g, V, b2);
    // h = x @ W_in.T + b_in            [50000 x 96], K=256
    gemm_nt_bias<<<dim3((NNODES + 63) / 64, 1), 256, 0, stream>>>(x, W_in, b_in, h, NNODES, INDIM, HIDDEN);
    // P = h @ V.T + bias2              [50000 x 192], K=96  (p_d | p_s, pre-scaled)
    gemm_nt_bias<<<dim3((NNODES + 63) / 64, 2), 256, 0, stream>>>(h, V, b2, P, NNODES, HIDDEN, 192);
    // edges: a + scatter
    edge_kernel<<<dim3((NEDGES * 24 + 255) / 256), 256, 0, stream>>>(P, h, dvec, src, dst, a_out, zac);
    // classifier + log_softmax
    clf_kernel<<<dim3((NNODES + 255) / 256), 256, 0, stream>>>(zac, W_c, b_c, z_out, NNODES);
}

// Round 2
// 741.202 us; speedup vs baseline: 2.0137x; 2.0137x over previous
//
#include <hip/hip_runtime.h>
#include <math.h>

#define HIDDEN 96
#define NNODES 50000
#define NEDGES 800000
#define INDIM  256
#define RS 0.07216878364870323f   // 1/sqrt(2*HIDDEN)

// ---------------------------------------------------------------------------
// Repack W_gate [96][192] into V [192][96]: V[j][k] = Wg[j][k]*RS (j<96),
// V[96+j][k] = Wg[j][96+k]*RS; bias2 = [b_gate*RS, 0]. Folds the 1/sqrt(192)
// scale so the edge pass is just tanh(pd + ps).
// ---------------------------------------------------------------------------
__global__ void repack_kernel(const float* __restrict__ Wg, const float* __restrict__ bg,
                              float* __restrict__ V, float* __restrict__ bias2) {
    int idx = blockIdx.x * 256 + threadIdx.x;
    if (idx < 192 * 96) {
        int j = idx / 96, k = idx % 96;
        float v = (j < 96) ? Wg[j * 192 + k] : Wg[(j - 96) * 192 + 96 + k];
        V[idx] = v * RS;
    }
    if (idx < 192) bias2[idx] = (idx < 96) ? bg[idx] * RS : 0.0f;
}

// ---------------------------------------------------------------------------
// C[M][ldc] = A[M][K] @ B[NB][K]^T + bias.  BM=128, BN=96, BK=32, 256 thr,
// 8x6 micro-tile: 192 FMA per 14 LDS b128 reads per k4 step.
// ---------------------------------------------------------------------------
__global__ __launch_bounds__(256) void gemm_nt_bias(
    const float* __restrict__ A, const float* __restrict__ B,
    const float* __restrict__ bias, float* __restrict__ C,
    int M, int K, int ldc) {
    __shared__ float As[128][36];
    __shared__ float Bs[96][36];
    const int tid = threadIdx.x;
    const int m0 = blockIdx.x * 128;
    const int n0 = blockIdx.y * 96;
    const int te = tid >> 4;       // 0..15 -> rows 8*te..8*te+7
    const int tc = tid & 15;       // 0..15 -> cols 6*tc..6*tc+5
    const int ra = tid >> 3;       // 0..31 load row
    const int ka = (tid & 7) * 4;  // k offset (float4)

    float acc[8][6];
#pragma unroll
    for (int i = 0; i < 8; i++)
#pragma unroll
        for (int j = 0; j < 6; j++) acc[i][j] = 0.0f;

    for (int k0 = 0; k0 < K; k0 += 32) {
#pragma unroll
        for (int r = 0; r < 4; r++) {
            int row = m0 + ra + r * 32;
            float4 v = make_float4(0, 0, 0, 0);
            if (row < M) v = *(const float4*)&A[(size_t)row * K + k0 + ka];
            *(float4*)&As[ra + r * 32][ka] = v;
        }
#pragma unroll
        for (int r = 0; r < 3; r++) {
            int row = n0 + ra + r * 32;   // always valid by grid construction
            float4 v = *(const float4*)&B[(size_t)row * K + k0 + ka];
            *(float4*)&Bs[ra + r * 32][ka] = v;
        }
        __syncthreads();
#pragma unroll
        for (int k4 = 0; k4 < 32; k4 += 4) {
            float4 af[8], bf[6];
#pragma unroll
            for (int i = 0; i < 8; i++) af[i] = *(float4*)&As[8 * te + i][k4];
#pragma unroll
            for (int j = 0; j < 6; j++) bf[j] = *(float4*)&Bs[6 * tc + j][k4];
#pragma unroll
            for (int i = 0; i < 8; i++)
#pragma unroll
                for (int j = 0; j < 6; j++)
                    acc[i][j] += af[i].x * bf[j].x + af[i].y * bf[j].y +
                                 af[i].z * bf[j].z + af[i].w * bf[j].w;
        }
        __syncthreads();
    }
#pragma unroll
    for (int i = 0; i < 8; i++) {
        int row = m0 + 8 * te + i;
        if (row < M) {
#pragma unroll
            for (int j = 0; j < 6; j++) {
                int col = n0 + 6 * tc + j;
                C[(size_t)row * ldc + col] = acc[i][j] + bias[col];
            }
        }
    }
}

// ---------------------------------------------------------------------------
// CSR build: histogram of dst -> block scan -> scatter edge ids.
// ---------------------------------------------------------------------------
__global__ void hist_kernel(const int* __restrict__ dst, int* __restrict__ counts) {
    int i = blockIdx.x * 256 + threadIdx.x;
    if (i < NEDGES) atomicAdd(&counts[dst[i]], 1);
}

__global__ __launch_bounds__(512) void scan1_kernel(const int* __restrict__ counts,
                                                    int* __restrict__ offsets,
                                                    int* __restrict__ btot) {
    __shared__ int sh[512];
    int tid = threadIdx.x;
    int i = blockIdx.x * 512 + tid;
    int v = (i < NNODES) ? counts[i] : 0;
    sh[tid] = v;
    __syncthreads();
    for (int off = 1; off < 512; off <<= 1) {
        int tmp = 0;
        if (tid >= off) tmp = sh[tid - off];
        __syncthreads();
        if (tid >= off) sh[tid] += tmp;
        __syncthreads();
    }
    if (i < NNODES) offsets[i] = sh[tid] - v;     // exclusive within block
    if (tid == 511) btot[blockIdx.x] = sh[511];
}

__global__ __launch_bounds__(128) void scan2_kernel(int* __restrict__ btot, int nb) {
    __shared__ int sh[128];
    int tid = threadIdx.x;
    int v = (tid < nb) ? btot[tid] : 0;
    sh[tid] = v;
    __syncthreads();
    for (int off = 1; off < 128; off <<= 1) {
        int tmp = 0;
        if (tid >= off) tmp = sh[tid - off];
        __syncthreads();
        if (tid >= off) sh[tid] += tmp;
        __syncthreads();
    }
    if (tid < nb) btot[tid] = sh[tid] - v;        // exclusive over blocks
}

__global__ __launch_bounds__(512) void scan3_kernel(int* __restrict__ offsets,
                                                    const int* __restrict__ btot) {
    int i = blockIdx.x * 512 + threadIdx.x;
    if (i < NNODES) offsets[i] += btot[blockIdx.x];
    if (i == 0) offsets[NNODES] = NEDGES;
}

__global__ void scatter_kernel(const int* __restrict__ src, const int* __restrict__ dst,
                               const int* __restrict__ offsets, int* __restrict__ cursor,
                               int* __restrict__ eidx, int* __restrict__ esrc) {
    int e = blockIdx.x * 256 + threadIdx.x;
    if (e < NEDGES) {
        int t = dst[e];
        int pos = offsets[t] + atomicAdd(&cursor[t], 1);
        eidx[pos] = e;
        esrc[pos] = src[e];
    }
}

// ---------------------------------------------------------------------------
// Aggregation: 24-lane group per dst node (float4 chunk per lane). Iterates
// the node's incoming edges: a = tanh(pd + ps) -> a_out; z accumulated in
// registers (NO atomics). Classifier + log_softmax fused via LDS reduction.
// ---------------------------------------------------------------------------
#define GPB 32   // node groups per block
#define TPG 24   // threads per group (24 x float4 = 96 cols)
__global__ __launch_bounds__(768) void agg_kernel(
    const float* __restrict__ P, const float* __restrict__ h,
    const float* __restrict__ dvec, const int* __restrict__ offsets,
    const int* __restrict__ eidx, const int* __restrict__ esrc,
    const float* __restrict__ Wc, const float* __restrict__ bc,
    float* __restrict__ a_out, float* __restrict__ z_out) {
    __shared__ float red0[GPB * TPG];
    __shared__ float red1[GPB * TPG];
    const int t = threadIdx.x;
    const int g = t / TPG;
    const int c = t % TPG;
    const int node = blockIdx.x * GPB + g;
    float s0 = 0.0f, s1 = 0.0f;
    if (node < NNODES) {
        float4 pd = *(const float4*)&P[(size_t)node * 192 + 4 * c];
        float dt = dvec[node];
        int start = offsets[node], end = offsets[node + 1];
        float4 z4 = make_float4(0, 0, 0, 0);
        for (int i = start; i < end; i++) {
            int e = eidx[i];
            int s = esrc[i];
            float4 ps = *(const float4*)&P[(size_t)s * 192 + 96 + 4 * c];
            float4 hs = *(const float4*)&h[(size_t)s * 96 + 4 * c];
            float ee = dt * dvec[s];
            float4 a4;
            a4.x = tanhf(pd.x + ps.x);
            a4.y = tanhf(pd.y + ps.y);
            a4.z = tanhf(pd.z + ps.z);
            a4.w = tanhf(pd.w + ps.w);
            *(float4*)&a_out[(size_t)e * 96 + 4 * c] = a4;
            z4.x += hs.x * a4.x * ee;
            z4.y += hs.y * a4.y * ee;
            z4.z += hs.z * a4.z * ee;
            z4.w += hs.w * a4.w * ee;
        }
        float4 w0 = *(const float4*)&Wc[4 * c];
        float4 w1 = *(const float4*)&Wc[96 + 4 * c];
        s0 = z4.x * w0.x + z4.y * w0.y + z4.z * w0.z + z4.w * w0.w;
        s1 = z4.x * w1.x + z4.y * w1.y + z4.z * w1.z + z4.w * w1.w;
    }
    red0[t] = s0;
    red1[t] = s1;
    __syncthreads();
    if (c == 0 && node < NNODES) {
        float a0 = bc[0], a1 = bc[1];
#pragma unroll
        for (int k = 0; k < TPG; k++) { a0 += red0[t + k]; a1 += red1[t + k]; }
        float m = fmaxf(a0, a1);
        float lse = m + logf(expf(a0 - m) + expf(a1 - m));
        z_out[2 * node + 0] = a0 - lse;
        z_out[2 * node + 1] = a1 - lse;
    }
}

extern "C" void kernel_launch(void* const* d_in, const int* in_sizes, int n_in,
                              void* d_out, int out_size, void* d_ws, size_t ws_size,
                              hipStream_t stream) {
    const float* x    = (const float*)d_in[0];
    const float* dvec = (const float*)d_in[1];
    const int*   src  = (const int*)d_in[2];
    const int*   dst  = (const int*)d_in[3];
    const float* W_in = (const float*)d_in[4];
    const float* b_in = (const float*)d_in[5];
    const float* W_g  = (const float*)d_in[6];
    const float* b_g  = (const float*)d_in[7];
    const float* W_c  = (const float*)d_in[8];
    const float* b_c  = (const float*)d_in[9];

    float* z_out = (float*)d_out;                 // [50000*2]
    float* a_out = (float*)d_out + 2 * NNODES;    // [800000*96]

    char* ws = (char*)d_ws;
    float* h       = (float*)(ws);                 // 19,200,000 B
    float* P       = (float*)(ws + 19200000);      // 38,400,000 B
    float* V       = (float*)(ws + 57600000);      // 73,728 B
    float* b2      = (float*)(ws + 57673728);      // 1,024 B (768 used)
    int*   offsets = (int*)  (ws + 57674752);      // 200,064 B (50001 used)
    int*   counts  = (int*)  (ws + 57874816);      // 200,064 B
    int*   cursor  = (int*)  (ws + 58074880);      // 200,064 B
    int*   btot    = (int*)  (ws + 58274944);      // 512 B (98 used)
    int*   eidx    = (int*)  (ws + 58275456);      // 3,200,000 B
    int*   esrc    = (int*)  (ws + 61475456);      // 3,200,000 B
    // total 64,675,456 B

    hipMemsetAsync(counts, 0, NNODES * sizeof(int), stream);
    hipMemsetAsync(cursor, 0, NNODES * sizeof(int), stream);

    repack_kernel<<<dim3((192 * 96 + 255) / 256), 256, 0, stream>>>(W_g, b_g, V, b2);
    // h = x @ W_in.T + b_in   [50000 x 96], K=256
    gemm_nt_bias<<<dim3((NNODES + 127) / 128, 1), 256, 0, stream>>>(x, W_in, b_in, h, NNODES, INDIM, HIDDEN);
    // P = h @ V.T + bias2     [50000 x 192], K=96
    gemm_nt_bias<<<dim3((NNODES + 127) / 128, 2), 256, 0, stream>>>(h, V, b2, P, NNODES, HIDDEN, 192);

    // CSR by dst
    const int NB = (NNODES + 511) / 512;  // 98
    hist_kernel<<<dim3((NEDGES + 255) / 256), 256, 0, stream>>>(dst, counts);
    scan1_kernel<<<dim3(NB), 512, 0, stream>>>(counts, offsets, btot);
    scan2_kernel<<<dim3(1), 128, 0, stream>>>(btot, NB);
    scan3_kernel<<<dim3(NB), 512, 0, stream>>>(offsets, btot);
    scatter_kernel<<<dim3((NEDGES + 255) / 256), 256, 0, stream>>>(src, dst, offsets, cursor, eidx, esrc);

    // Edge pass + scatter-free aggregation + fused classifier/log_softmax
    agg_kernel<<<dim3((NNODES + GPB - 1) / GPB), GPB * TPG, 0, stream>>>(
        P, h, dvec, offsets, eidx, esrc, W_c, b_c, a_out, z_out);
}